// Round 2
// baseline (951.011 us; speedup 1.0000x reference)
//
#include <hip/hip_runtime.h>

#define D 64
#define EPS 1e-12f

typedef unsigned short u16;

__device__ __forceinline__ float bf2f(u16 u) {
    return __uint_as_float(((unsigned)u) << 16);
}
// round-to-nearest-even f32 -> bf16 (finite values)
__device__ __forceinline__ u16 f2bf(float f) {
    unsigned u = __float_as_uint(f);
    u += 0x7fffu + ((u >> 16) & 1u);
    return (u16)(u >> 16);
}
__device__ __forceinline__ float loadf(const void* p, size_t i, int bf) {
    return bf ? bf2f(((const u16*)p)[i]) : ((const float*)p)[i];
}

#define FMA4(acc, s, v)                       \
    do {                                      \
        acc.x = fmaf((s), (v).x, acc.x);      \
        acc.y = fmaf((s), (v).y, acc.y);      \
        acc.z = fmaf((s), (v).z, acc.z);      \
        acc.w = fmaf((s), (v).w, acc.w);      \
    } while (0)

// Detect input dtype: bf16 N(0,1) data never has exponent >= 0xC0; f32 data
// read as u16 halves triggers constantly. flag=1 -> bf16, flag=0 -> f32.
__global__ __launch_bounds__(64) void detect_kernel(const u16* __restrict__ x,
                                                    int* __restrict__ flag) {
    int lane = threadIdx.x;
    int bad = 0;
    for (int i = 0; i < 64; ++i) {
        u16 u = x[lane * 64 + i];
        int e = (u >> 7) & 0xFF;
        if (e >= 0xC0) bad = 1;
    }
    unsigned long long b = __ballot(bad);
    if (lane == 0) *flag = (b == 0ull) ? 1 : 0;
}

// Kernel A: per-node L2 normalize; agg = xn (f32); store norm and 1/max(norm,eps)
__global__ __launch_bounds__(256) void norm_init_kernel(
    const void* __restrict__ xin, float* __restrict__ agg,
    float* __restrict__ nx, float* __restrict__ rnx, int N,
    const int* __restrict__ flagp)
{
    const int bf = *flagp;
    int node = (int)((blockIdx.x * blockDim.x + threadIdx.x) >> 6);
    int lane = threadIdx.x & 63;
    if (node >= N) return;
    size_t idx = (size_t)node * D + lane;
    float v = loadf(xin, idx, bf);
    float s = v * v;
    s += __shfl_xor(s, 32); s += __shfl_xor(s, 16); s += __shfl_xor(s, 8);
    s += __shfl_xor(s, 4);  s += __shfl_xor(s, 2);  s += __shfl_xor(s, 1);
    float n = sqrtf(s);
    float inv = 1.0f / fmaxf(n, EPS);
    agg[idx] = v * inv;
    if (lane == 0) { nx[node] = n; rnx[node] = inv; }
}

// Kernel B: edge scatter-add. One wave per edge, lane = feature.
// Recomputes xn[src] on the fly (x * rnx) -- bit-identical to agg's init value.
__global__ __launch_bounds__(256) void scatter_kernel(
    const int* __restrict__ src, const int* __restrict__ dst,
    const void* __restrict__ xin, const float* __restrict__ rnx,
    float* __restrict__ agg, int E, const int* __restrict__ flagp)
{
    const int bf = *flagp;
    int e = (int)((blockIdx.x * blockDim.x + threadIdx.x) >> 6);
    int lane = threadIdx.x & 63;
    if (e >= E) return;
    int s = src[e], d = dst[e];
    float v = loadf(xin, (size_t)s * D + lane, bf);
    atomicAdd(&agg[(size_t)d * D + lane], v * rnx[s]);
}

// Kernel C: msg-norm + two 64x64 GEMMs + final l2norm (+optional relu).
// Block = 256 threads = 4 waves; each wave handles 4 nodes/group, 4 groups.
// Lane = sub*16 + cg; lane computes out cols [cg*4 .. cg*4+3] of node (base+sub).
__global__ __launch_bounds__(256) void epilogue_kernel(
    const float* __restrict__ agg, const float* __restrict__ nx,
    const void* __restrict__ xin,
    const void* __restrict__ wl, const void* __restrict__ bl,
    const void* __restrict__ wr, const void* __restrict__ scale_p,
    void* __restrict__ out, int N, const int* __restrict__ flagp, int relu)
{
    __shared__ float lds_wl[D * D];   // transposed: lds_wl[k*64+j] = Wl[j][k]
    __shared__ float lds_wr[D * D];
    __shared__ float lds_bl[D];
    __shared__ float msgbuf[4][4 * 68];  // [wave][sub*68 + k], pad 68
    __shared__ float xrbuf[4][4 * 68];

    const int bf = *flagp;
    const int t = threadIdx.x;
    for (int idx = t; idx < D * D; idx += 256) {
        int j = idx >> 6, k = idx & 63;
        lds_wl[k * D + j] = loadf(wl, idx, bf);
        lds_wr[k * D + j] = loadf(wr, idx, bf);
    }
    if (t < D) lds_bl[t] = loadf(bl, t, bf);
    __syncthreads();

    const float scl = loadf(scale_p, 0, bf);
    const int w = t >> 6, lane = t & 63;
    const int sub = lane >> 4, cg = lane & 15;
    float* mrow = &msgbuf[w][sub * 68];
    float* xrow = &xrbuf[w][sub * 68];

    for (int g = 0; g < 4; ++g) {
        int node = blockIdx.x * 64 + (w * 4 + g) * 4 + sub;
        bool valid = node < N;
        int nc = valid ? node : N - 1;

        // msg = l2norm(agg) * ||x|| * scale
        float4 v4 = ((const float4*)(agg + (size_t)nc * D))[cg];
        float s = v4.x * v4.x + v4.y * v4.y + v4.z * v4.z + v4.w * v4.w;
        s += __shfl_xor(s, 1); s += __shfl_xor(s, 2);
        s += __shfl_xor(s, 4); s += __shfl_xor(s, 8);
        float minv = scl * nx[nc] / fmaxf(sqrtf(s), EPS);

        float4 x4;
        if (bf) {
            ushort4 u = ((const ushort4*)((const u16*)xin + (size_t)nc * D))[cg];
            x4 = make_float4(bf2f(u.x), bf2f(u.y), bf2f(u.z), bf2f(u.w));
        } else {
            x4 = ((const float4*)((const float*)xin + (size_t)nc * D))[cg];
        }

        // wave-local LDS exchange (producer/consumer same wave, in-order LDS)
        *((float4*)(mrow + cg * 4)) =
            make_float4(v4.x * minv, v4.y * minv, v4.z * minv, v4.w * minv);
        *((float4*)(xrow + cg * 4)) = x4;

        float4 acc = ((const float4*)lds_bl)[cg];
#pragma unroll
        for (int k4 = 0; k4 < 16; ++k4) {
            float4 m4  = *((const float4*)(mrow + k4 * 4));
            float4 xr4 = *((const float4*)(xrow + k4 * 4));
            const float* wlp = lds_wl + (k4 * 4) * D + cg * 4;
            const float* wrp = lds_wr + (k4 * 4) * D + cg * 4;
            float4 a;
            a = *((const float4*)(wlp + 0 * D)); FMA4(acc, m4.x, a);
            a = *((const float4*)(wlp + 1 * D)); FMA4(acc, m4.y, a);
            a = *((const float4*)(wlp + 2 * D)); FMA4(acc, m4.z, a);
            a = *((const float4*)(wlp + 3 * D)); FMA4(acc, m4.w, a);
            a = *((const float4*)(wrp + 0 * D)); FMA4(acc, xr4.x, a);
            a = *((const float4*)(wrp + 1 * D)); FMA4(acc, xr4.y, a);
            a = *((const float4*)(wrp + 2 * D)); FMA4(acc, xr4.z, a);
            a = *((const float4*)(wrp + 3 * D)); FMA4(acc, xr4.w, a);
        }

        float s2 = acc.x * acc.x + acc.y * acc.y + acc.z * acc.z + acc.w * acc.w;
        s2 += __shfl_xor(s2, 1); s2 += __shfl_xor(s2, 2);
        s2 += __shfl_xor(s2, 4); s2 += __shfl_xor(s2, 8);
        float inv = 1.0f / fmaxf(sqrtf(s2), EPS);
        float4 r = make_float4(acc.x * inv, acc.y * inv, acc.z * inv, acc.w * inv);
        if (relu) {
            r.x = fmaxf(r.x, 0.f); r.y = fmaxf(r.y, 0.f);
            r.z = fmaxf(r.z, 0.f); r.w = fmaxf(r.w, 0.f);
        }
        if (valid) {
            if (bf) {
                ushort4 o = make_ushort4(f2bf(r.x), f2bf(r.y), f2bf(r.z), f2bf(r.w));
                ((ushort4*)((u16*)out + (size_t)node * D))[cg] = o;
            } else {
                ((float4*)((float*)out + (size_t)node * D))[cg] = r;
            }
        }
    }
}

extern "C" void kernel_launch(void* const* d_in, const int* in_sizes, int n_in,
                              void* d_out, int out_size, void* d_ws, size_t ws_size,
                              hipStream_t stream)
{
    const void* x   = d_in[0];
    const void* Wl0 = d_in[1];
    const void* bl0 = d_in[2];
    const void* Wr0 = d_in[3];
    const void* sc0 = d_in[4];
    const void* Wl1 = d_in[5];
    const void* bl1 = d_in[6];
    const void* Wr1 = d_in[7];
    const void* sc1 = d_in[8];
    const int* ei   = (const int*)d_in[9];

    const int N = in_sizes[0] / D;
    const int E = in_sizes[9] / 2;
    const int* src = ei;
    const int* dst = ei + E;

    // workspace (26.4 MB): agg f32 (N*D) | nx f32 (N) | rnx f32 (N) | flag int
    float* agg = (float*)d_ws;
    float* nx  = agg + (size_t)N * D;
    float* rnx = nx + N;
    int* flag  = (int*)(rnx + N);

    // inter-layer h lives in d_out (layer-1 epilogue reads only its own row
    // of h before overwriting it; all cross-node h reads happen earlier).
    void* h = d_out;

    dim3 blk(256);
    int gridA = (N + 3) / 4;
    int gridB = (E + 3) / 4;
    int gridC = (N + 63) / 64;

    detect_kernel<<<1, 64, 0, stream>>>((const u16*)x, flag);

    // ---- layer 0 (input x, output h -> d_out, relu) ----
    norm_init_kernel<<<gridA, blk, 0, stream>>>(x, agg, nx, rnx, N, flag);
    scatter_kernel<<<gridB, blk, 0, stream>>>(src, dst, x, rnx, agg, E, flag);
    epilogue_kernel<<<gridC, blk, 0, stream>>>(agg, nx, x, Wl0, bl0, Wr0, sc0,
                                               h, N, flag, 1);

    // ---- layer 1 (input h = d_out, output d_out, no relu) ----
    norm_init_kernel<<<gridA, blk, 0, stream>>>(h, agg, nx, rnx, N, flag);
    scatter_kernel<<<gridB, blk, 0, stream>>>(src, dst, h, rnx, agg, E, flag);
    epilogue_kernel<<<gridC, blk, 0, stream>>>(agg, nx, h, Wl1, bl1, Wr1, sc1,
                                               d_out, N, flag, 0);
}